// Round 5
// baseline (317.872 us; speedup 1.0000x reference)
//
#include <hip/hip_runtime.h>
#include <math.h>

// LoRA-MLP, fp32 in/out. Fold rank-16 LoRA into weights (K=1), then two
// bf16 MFMA GEMMs: h = gelu(x@W1eff^T + b1); out = h@W2eff^T + b2.
#define M_ROWS 12608   // 64*197
#define D_DIM  768
#define H_DIM  3072

typedef __bf16 bf16_t;
typedef __bf16 bf16x8 __attribute__((ext_vector_type(8)));
typedef float  f32x4  __attribute__((ext_vector_type(4)));

__device__ __forceinline__ float gelu_fast(float v) {
  float v2 = v * v;
  float z = v * fmaf(0.044715f, v2, 1.0f);
  float e = __expf(-1.5957691216057308f * z);
  return v * __builtin_amdgcn_rcpf(1.0f + e);
}

// Async global->LDS 16B copy. LDS dest must be wave-uniform base + lane*16.
__device__ __forceinline__ void gld16(const bf16_t* g, char* l) {
  __builtin_amdgcn_global_load_lds(
      (const __attribute__((address_space(1))) void*)g,
      (__attribute__((address_space(3))) void*)l, 16, 0, 0);
}

__global__ void cast_f32_bf16_kernel(const float* __restrict__ in,
                                     bf16_t* __restrict__ out, long n) {
  long i = ((long)blockIdx.x * 256 + threadIdx.x) * 4;
  if (i + 3 < n) {
    float4 v = *(const float4*)(in + i);
    out[i + 0] = (bf16_t)v.x; out[i + 1] = (bf16_t)v.y;
    out[i + 2] = (bf16_t)v.z; out[i + 3] = (bf16_t)v.w;
  } else {
    for (; i < n; ++i) out[i] = (bf16_t)in[i];
  }
}

// Weff[o][i] = W[o][i] + sum_r Bm[o][r]*A[r][i]  (fp32 in, bf16 out)
__global__ void fold_lora_kernel(const float* __restrict__ W,
                                 const float* __restrict__ A,
                                 const float* __restrict__ Bm,
                                 bf16_t* __restrict__ Weff,
                                 int OUT, int IN) {
  long idx = (long)blockIdx.x * 256 + threadIdx.x;
  if (idx >= (long)OUT * IN) return;
  int o = (int)(idx / IN);
  int i = (int)(idx - (long)o * IN);
  float s = W[idx];
#pragma unroll
  for (int r = 0; r < 16; ++r)
    s += Bm[o * 16 + r] * A[r * IN + i];
  Weff[idx] = (bf16_t)s;
}

// ---------------------------------------------------------------------------
// GEMM1: m201-style 256x256 8-phase pipeline. C = gelu(A@B^T + bias), bf16.
// BM=BN=256, BK=64; 8 waves 2Mx4N (wave tile 128x64 -> 2.67 MFMA/ds_read vs
// 2.0 at 64x64 -- fixes the per-block LDS-issue bound); 512 threads.
// LDS 128 KiB: 2 buffers x {A 2x[256][32], B 2x[256][32]} bf16, staged in
// 4 quarter-units/K-tile (B-kh0, A-kh0, B-kh1, A-kh1; 2 gld16/thread each).
// Swizzle: within a unit, row r slot s holds global k-chunk s^((r>>1)&3)
// (2-bit involution; ds_read_b128 verified 2-way = free; linear gld16 dest
// with pre-swizzled global source, rule 21).
// Waits (derived): unit staged at phase g is first read at g+4. vmcnt(4)
// BEFORE the closing barrier of p1/p3 => every wave confirms all units
// except the last 2 landed, barrier publishes => next 2 phases' reads safe.
// Steady state never drains (T4); tail NT-1.p1 uses vmcnt(0).
// Prologue: 4 units + vmcnt(4) + barrier (m201's documented prologue).
// Phases p0..p3 = (ks,nh): {reads, stage 1 unit, barrier, lgkmcnt(0)+SB
// (rule 18), setprio(1) 16 MFMA setprio(0), [vmcnt] barrier}.
// Grid 600 = 8 XCD x 75, bijective: XCD covers contiguous 75 blocks
// (1.5 B-col panels L2-resident).
// ---------------------------------------------------------------------------
__global__ __launch_bounds__(512, 2) void gemm1_256(
    const bf16_t* __restrict__ Amat, const bf16_t* __restrict__ Bmat,
    const float* __restrict__ bias, bf16_t* __restrict__ Cmat,
    int Mrows, int Ncols, int Kd) {
  __shared__ char smem[131072];
  bf16_t* lds = (bf16_t*)smem;
  float* sT = (float*)smem;      // epilogue scratch [64][257] f32

  const int xcd = blockIdx.x & 7, t6 = blockIdx.x >> 3;
  const int wg = xcd * 75 + t6;            // bijective (600 = 8*75)
  const int rowb = wg % 50, colb = wg / 50;
  const int row0 = rowb * 256, col0 = colb * 256;

  const int tid = threadIdx.x, lane = tid & 63, wave = tid >> 6;
  const int wm = wave & 1, wn = wave >> 1;   // wave tile: rows wm*128, cols wn*64

  // staging bases: unit = 256 rows x 32 k = 1024 chunks, 2/thread.
  // chunk c: row c>>2, slot c&3 holds global k-chunk (c&3)^((row>>1)&3).
  const bf16_t* gA[2]; const bf16_t* gB[2]; int ldsc[2];
#pragma unroll
  for (int q = 0; q < 2; ++q) {
    int c = tid + q * 512;
    int r = c >> 2, kk = (c & 3) ^ ((r >> 1) & 3);
    int ra = row0 + r; if (ra > Mrows - 1) ra = Mrows - 1;  // M-edge clamp
    gA[q] = Amat + (size_t)ra * Kd + kk * 8;
    gB[q] = Bmat + (size_t)(col0 + r) * Kd + kk * 8;
    ldsc[q] = c * 16;
  }

  // fragment element-offsets within a 8192-elem k-half region.
  const int rl = lane & 15, kc = lane >> 4;
  int aoffs[8], boffs[4];
#pragma unroll
  for (int i = 0; i < 8; ++i) {
    int ra = wm * 128 + i * 16 + rl;
    aoffs[i] = ra * 32 + ((kc ^ ((ra >> 1) & 3)) * 8);
  }
#pragma unroll
  for (int i = 0; i < 4; ++i) {
    int rb = wn * 64 + i * 16 + rl;
    boffs[i] = rb * 32 + ((kc ^ ((rb >> 1) & 3)) * 8);
  }

  f32x4 acc[8][4] = {};
  const int NT = Kd / 64;   // 12
  int knext = 0;

  // byte layout per buffer b (base b*65536): A-kh0 [0,16K), A-kh1 [16K,32K),
  // B-kh0 [32K,48K), B-kh1 [48K,64K).
#define STAGE_A(kh, sb)  do {                                               \
    gld16(gA[0] + knext + (kh) * 32, smem + (sb) + (kh) * 16384 + ldsc[0]); \
    gld16(gA[1] + knext + (kh) * 32, smem + (sb) + (kh) * 16384 + ldsc[1]); \
  } while (0)
#define STAGE_B(kh, sb)  do {                                               \
    gld16(gB[0] + knext + (kh) * 32, smem + (sb) + 32768 + (kh) * 16384 + ldsc[0]); \
    gld16(gB[1] + knext + (kh) * 32, smem + (sb) + 32768 + (kh) * 16384 + ldsc[1]); \
  } while (0)
#define SB __builtin_amdgcn_sched_barrier(0)

  // prologue: stage K-tile 0's 4 units -> buf0; publish first 2 units.
  STAGE_B(0, 0); STAGE_A(0, 0); STAGE_B(1, 0); STAGE_A(1, 0);
  knext = 64;
  asm volatile("s_waitcnt vmcnt(4)" ::: "memory"); SB;
  __builtin_amdgcn_s_barrier();

  for (int it = 0; it < NT; ++it) {
    const bool st = (it + 1 < NT);
    const int cbe = (it & 1) * 32768;       // compute buffer (elements)
    const int sb = ((it + 1) & 1) * 65536;  // stage buffer (bytes)
    bf16x8 af[8], bfr[2];

    // ---- p0: ks=0, nh=0 ----
#pragma unroll
    for (int i = 0; i < 8; ++i) af[i] = *(const bf16x8*)(lds + cbe + aoffs[i]);
#pragma unroll
    for (int i = 0; i < 2; ++i) bfr[i] = *(const bf16x8*)(lds + cbe + 16384 + boffs[i]);
    if (st) STAGE_B(0, sb);
    __builtin_amdgcn_s_barrier();
    asm volatile("s_waitcnt lgkmcnt(0)" ::: "memory"); SB;
    __builtin_amdgcn_s_setprio(1);
#pragma unroll
    for (int mi = 0; mi < 8; ++mi)
#pragma unroll
      for (int ni = 0; ni < 2; ++ni)
        acc[mi][ni] = __builtin_amdgcn_mfma_f32_16x16x32_bf16(af[mi], bfr[ni], acc[mi][ni], 0, 0, 0);
    __builtin_amdgcn_s_setprio(0);
    __builtin_amdgcn_s_barrier();

    // ---- p1: ks=0, nh=1 ----
#pragma unroll
    for (int i = 0; i < 2; ++i) bfr[i] = *(const bf16x8*)(lds + cbe + 16384 + boffs[i + 2]);
    if (st) STAGE_A(0, sb);
    __builtin_amdgcn_s_barrier();
    asm volatile("s_waitcnt lgkmcnt(0)" ::: "memory"); SB;
    __builtin_amdgcn_s_setprio(1);
#pragma unroll
    for (int mi = 0; mi < 8; ++mi)
#pragma unroll
      for (int ni = 0; ni < 2; ++ni)
        acc[mi][ni + 2] = __builtin_amdgcn_mfma_f32_16x16x32_bf16(af[mi], bfr[ni], acc[mi][ni + 2], 0, 0, 0);
    __builtin_amdgcn_s_setprio(0);
    // publish kh1 units of THIS K-tile (staged 2 phases before p2 reads)
    if (st) { asm volatile("s_waitcnt vmcnt(4)" ::: "memory"); }
    else    { asm volatile("s_waitcnt vmcnt(0)" ::: "memory"); }
    SB;
    __builtin_amdgcn_s_barrier();

    // ---- p2: ks=1, nh=0 ----
#pragma unroll
    for (int i = 0; i < 8; ++i) af[i] = *(const bf16x8*)(lds + cbe + 8192 + aoffs[i]);
#pragma unroll
    for (int i = 0; i < 2; ++i) bfr[i] = *(const bf16x8*)(lds + cbe + 16384 + 8192 + boffs[i]);
    if (st) STAGE_B(1, sb);
    __builtin_amdgcn_s_barrier();
    asm volatile("s_waitcnt lgkmcnt(0)" ::: "memory"); SB;
    __builtin_amdgcn_s_setprio(1);
#pragma unroll
    for (int mi = 0; mi < 8; ++mi)
#pragma unroll
      for (int ni = 0; ni < 2; ++ni)
        acc[mi][ni] = __builtin_amdgcn_mfma_f32_16x16x32_bf16(af[mi], bfr[ni], acc[mi][ni], 0, 0, 0);
    __builtin_amdgcn_s_setprio(0);
    __builtin_amdgcn_s_barrier();

    // ---- p3: ks=1, nh=1 ----
#pragma unroll
    for (int i = 0; i < 2; ++i) bfr[i] = *(const bf16x8*)(lds + cbe + 16384 + 8192 + boffs[i + 2]);
    if (st) STAGE_A(1, sb);
    __builtin_amdgcn_s_barrier();
    asm volatile("s_waitcnt lgkmcnt(0)" ::: "memory"); SB;
    __builtin_amdgcn_s_setprio(1);
#pragma unroll
    for (int mi = 0; mi < 8; ++mi)
#pragma unroll
      for (int ni = 0; ni < 2; ++ni)
        acc[mi][ni + 2] = __builtin_amdgcn_mfma_f32_16x16x32_bf16(af[mi], bfr[ni], acc[mi][ni + 2], 0, 0, 0);
    __builtin_amdgcn_s_setprio(0);
    // publish next K-tile's kh0 units (staged at p0/p1, read at next p0)
    if (st) { asm volatile("s_waitcnt vmcnt(4)" ::: "memory"); SB; }
    __builtin_amdgcn_s_barrier();

    knext += 64;
  }
#undef STAGE_A
#undef STAGE_B

  // epilogue: 4 passes of 64 rows; wm-matching waves stage f32 to LDS,
  // all threads gelu+bias and store bf16. C/D layout: col=lane&15,
  // row=(lane>>4)*4+reg [m89-verified].
  const int crow = (lane >> 4) * 4, ccol = lane & 15;
  __syncthreads();
#pragma unroll
  for (int p = 0; p < 4; ++p) {
    if (wm == (p >> 1)) {
#pragma unroll
      for (int s = 0; s < 4; ++s) {
        int mi = (p & 1) * 4 + s;
#pragma unroll
        for (int ni = 0; ni < 4; ++ni)
#pragma unroll
          for (int r = 0; r < 4; ++r)
            sT[(s * 16 + crow + r) * 257 + wn * 64 + ni * 16 + ccol] = acc[mi][ni][r];
      }
    }
    __syncthreads();
    const int lr = tid >> 3, seg = tid & 7;
    const int grow = row0 + p * 64 + lr;
    if (grow < Mrows) {
      const float* src = sT + lr * 257 + seg * 32;
      const float* bs = bias + col0 + seg * 32;
      bf16_t ov[32];
#pragma unroll
      for (int i = 0; i < 32; ++i) ov[i] = (bf16_t)gelu_fast(src[i] + bs[i]);
      bf16_t* dst = Cmat + (size_t)grow * Ncols + col0 + seg * 32;
#pragma unroll
      for (int k = 0; k < 4; ++k)
        *(bf16x8*)(dst + k * 8) = *(bf16x8*)(ov + k * 8);
    }
    __syncthreads();
  }
}

// ---------------------------------------------------------------------------
// GEMM2 (R2-exact, measured best): 128x128 2-phase gload_lds kernel.
// C[m][n] = sum_k A[m][k]*B[n][k] + bias[n], f32 out.
// ---------------------------------------------------------------------------
template <int SCHED, int SMEM_BYTES>
__global__ __launch_bounds__(256, 3) void gemm_kernel(
    const bf16_t* __restrict__ Amat, const bf16_t* __restrict__ Bmat,
    const float* __restrict__ bias, float* __restrict__ Cmat,
    int Mrows, int Ncols, int Kd) {
  __shared__ char smem[SMEM_BYTES];
  bf16_t* lds = (bf16_t*)smem;   // A: elements [0,8192), B: [8192,16384)

  int rowb, colb;
  const int xcd = blockIdx.x & 7, t = blockIdx.x >> 3;
  if (SCHED == 1) {
    colb = t / 13;
    rowb = (t % 13) * 8 + xcd;
    if (rowb >= 99) return;
  } else {                       // 3 cols x 25 rbands per XCD, col-fast
    rowb = (t / 3) * 4 + (xcd & 3);
    if (rowb >= 99) return;
    colb = (xcd >> 2) * 3 + (t % 3);
  }
  const int row0 = rowb * 128, col0 = colb * 128;

  const int tid = threadIdx.x, lane = tid & 63, wave = tid >> 6;
  const int wm = wave & 1, wn = wave >> 1;

  const bf16_t* gA[4]; const bf16_t* gB[4];
  int ldsA[4], ldsB[4];
#pragma unroll
  for (int q = 0; q < 4; ++q) {
    int c = tid + q * 256;
    int r = c >> 3, kkg = (c & 7) ^ (r & 7);
    int ra = row0 + r; if (ra > Mrows - 1) ra = Mrows - 1;
    gA[q] = Amat + (size_t)ra * Kd + kkg * 8;
    gB[q] = Bmat + (size_t)(col0 + r) * Kd + kkg * 8;
    ldsA[q] = c * 16;
    ldsB[q] = 16384 + c * 16;
  }

  const int rl = lane & 15, kc = lane >> 4;
  int aoffs[4], boffs[4];
#pragma unroll
  for (int i = 0; i < 4; ++i) {
    int ra = wm * 64 + i * 16 + rl;
    int rb = wn * 64 + i * 16 + rl;
    aoffs[i] = ra * 64 + ((kc ^ (ra & 7)) * 8);
    boffs[i] = 8192 + rb * 64 + ((kc ^ (rb & 7)) * 8);
  }

  f32x4 acc[4][4] = {};
  const int iters = Kd / 64;

#pragma unroll
  for (int q = 0; q < 4; ++q) {
    gld16(gA[q], smem + ldsA[q]);
    gld16(gB[q], smem + ldsB[q]);
    gA[q] += 64; gB[q] += 64;
  }
  __syncthreads();

  for (int it = 0; it < iters; ++it) {
#pragma unroll
    for (int ks = 0; ks < 2; ++ks) {
      bf16x8 af[4], bfr[4];
#pragma unroll
      for (int i = 0; i < 4; ++i) af[i] = *(const bf16x8*)(lds + (aoffs[i] ^ (ks * 32)));
#pragma unroll
      for (int i = 0; i < 4; ++i) bfr[i] = *(const bf16x8*)(lds + (boffs[i] ^ (ks * 32)));
#pragma unroll
      for (int mi = 0; mi < 4; ++mi)
#pragma unroll
        for (int ni = 0; ni < 4; ++ni)
          acc[mi][ni] = __builtin_amdgcn_mfma_f32_16x16x32_bf16(
              af[mi], bfr[ni], acc[mi][ni], 0, 0, 0);
    }
    if (it + 1 < iters) {
      __syncthreads();
#pragma unroll
      for (int q = 0; q < 4; ++q) {
        gld16(gA[q], smem + ldsA[q]);
        gld16(gB[q], smem + ldsB[q]);
        gA[q] += 64; gB[q] += 64;
      }
      __syncthreads();
    }
  }

  const int crow = (lane >> 4) * 4, ccol = lane & 15;
#pragma unroll
  for (int ni = 0; ni < 4; ++ni) {
    const int gc = col0 + wn * 64 + ni * 16 + ccol;
    const float bv = bias[gc];
#pragma unroll
    for (int mi = 0; mi < 4; ++mi) {
      const int gr = row0 + wm * 64 + mi * 16 + crow;
#pragma unroll
      for (int r = 0; r < 4; ++r) {
        const int row = gr + r;
        if (row < Mrows)
          Cmat[(size_t)row * Ncols + gc] = acc[mi][ni][r] + bv;
      }
    }
  }
}

extern "C" void kernel_launch(void* const* d_in, const int* in_sizes, int n_in,
                              void* d_out, int out_size, void* d_ws, size_t ws_size,
                              hipStream_t stream) {
  const float* x  = (const float*)d_in[0];
  const float* W1 = (const float*)d_in[1];
  const float* b1 = (const float*)d_in[2];
  const float* A1 = (const float*)d_in[3];
  const float* B1 = (const float*)d_in[4];
  const float* W2 = (const float*)d_in[5];
  const float* b2 = (const float*)d_in[6];
  const float* A2 = (const float*)d_in[7];
  const float* B2 = (const float*)d_in[8];
  float* out = (float*)d_out;

  char* ws = (char*)d_ws;
  bf16_t* xb    = (bf16_t*)ws;                             // 19,365,888 B (pad)
  bf16_t* W1eff = (bf16_t*)(ws + 19366144);                //  4,718,592 B
  bf16_t* W2eff = (bf16_t*)(ws + 19366144 + 4718592);      //  4,718,592 B
  bf16_t* hbuf  = (bf16_t*)(ws + 19366144 + 2 * 4718592);  // 77,463,552 B

  const long nx = (long)M_ROWS * D_DIM;
  cast_f32_bf16_kernel<<<(int)((nx / 4 + 255) / 256), 256, 0, stream>>>(x, xb, nx);

  const int foldBlocks = (H_DIM * D_DIM + 255) / 256;
  fold_lora_kernel<<<foldBlocks, 256, 0, stream>>>(W1, A1, B1, W1eff, H_DIM, D_DIM);
  fold_lora_kernel<<<foldBlocks, 256, 0, stream>>>(W2, A2, B2, W2eff, D_DIM, H_DIM);

  // GEMM1: 256x256 8-phase; grid 50 rbands x 12 cols = 600 = 8 XCD x 75
  gemm1_256<<<600, 512, 0, stream>>>(
      xb, W1eff, b1, hbuf, M_ROWS, H_DIM, D_DIM);
  // GEMM2: 99 rbands x 6 cols; two 4-XCD groups x 3 cols, col-fast -> 25*3*8
  gemm_kernel<2, 32768><<<600, 256, 0, stream>>>(
      hbuf, W2eff, b2, out, M_ROWS, D_DIM, H_DIM);
}

// Round 7
// 286.205 us; speedup vs baseline: 1.1106x; 1.1106x over previous
//
#include <hip/hip_runtime.h>
#include <math.h>

// LoRA-MLP, fp32 in/out. Fold rank-16 LoRA into weights (K=1), then two
// bf16 MFMA GEMMs: h = gelu(x@W1eff^T + b1); out = h@W2eff^T + b2.
#define M_ROWS 12608   // 64*197
#define D_DIM  768
#define H_DIM  3072

typedef __bf16 bf16_t;
typedef __bf16 bf16x8 __attribute__((ext_vector_type(8)));
typedef float  f32x4  __attribute__((ext_vector_type(4)));

// Fast GELU via sigmoid form of the tanh approximation (validated r6,
// absmax contribution ~3e-4 << threshold).
__device__ __forceinline__ float gelu_fast(float v) {
  float v2 = v * v;
  float z = v * fmaf(0.044715f, v2, 1.0f);
  float e = __expf(-1.5957691216057308f * z);
  return v * __builtin_amdgcn_rcpf(1.0f + e);
}

// Async global->LDS 16B copy. LDS dest must be wave-uniform base + lane*16.
__device__ __forceinline__ void gld16(const bf16_t* g, char* l) {
  __builtin_amdgcn_global_load_lds(
      (const __attribute__((address_space(1))) void*)g,
      (__attribute__((address_space(3))) void*)l, 16, 0, 0);
}

// ---------------------------------------------------------------------------
// Fused prep: ONE launch for {x cast, fold1, fold2} (independent work,
// whole blocks per branch). Saves 2 kernel launches (~10us each, rocprof.md).
//   blocks [0, 9456):      cast x (12608*768 f32 -> bf16), 4 elems/thread
//   blocks [9456, 18672):  W1eff = W1 + B1@A1  (3072x768)
//   blocks [18672, 27888): W2eff = W2 + B2@A2  (768x3072)
// 9456*1024 == 12608*768 and 9216*256 == 3072*768 exactly -> no guards.
// ---------------------------------------------------------------------------
#define CAST_BLOCKS 9456
#define FOLD_BLOCKS 9216

__device__ __forceinline__ void fold_body(const float* __restrict__ W,
                                          const float* __restrict__ A,
                                          const float* __restrict__ Bm,
                                          bf16_t* __restrict__ Weff,
                                          int IN, long idx) {
  int o = (int)(idx / IN);
  int i = (int)(idx - (long)o * IN);
  float s = W[idx];
#pragma unroll
  for (int r = 0; r < 16; ++r)
    s += Bm[o * 16 + r] * A[r * IN + i];
  Weff[idx] = (bf16_t)s;
}

__global__ __launch_bounds__(256) void prep_kernel(
    const float* __restrict__ x, bf16_t* __restrict__ xb,
    const float* __restrict__ W1, const float* __restrict__ A1,
    const float* __restrict__ B1, bf16_t* __restrict__ W1eff,
    const float* __restrict__ W2, const float* __restrict__ A2,
    const float* __restrict__ B2, bf16_t* __restrict__ W2eff) {
  const int b = blockIdx.x;
  if (b < CAST_BLOCKS) {
    long i = ((long)b * 256 + threadIdx.x) * 4;
    float4 v = *(const float4*)(x + i);
    xb[i + 0] = (bf16_t)v.x; xb[i + 1] = (bf16_t)v.y;
    xb[i + 2] = (bf16_t)v.z; xb[i + 3] = (bf16_t)v.w;
  } else if (b < CAST_BLOCKS + FOLD_BLOCKS) {
    long idx = (long)(b - CAST_BLOCKS) * 256 + threadIdx.x;
    fold_body(W1, A1, B1, W1eff, D_DIM, idx);
  } else {
    long idx = (long)(b - CAST_BLOCKS - FOLD_BLOCKS) * 256 + threadIdx.x;
    fold_body(W2, A2, B2, W2eff, H_DIM, idx);
  }
}

// ---------------------------------------------------------------------------
// GEMM1 (R2-exact, measured 90us / MfmaUtil 27.6): 128x128 2-phase
// gload_lds kernel, C = gelu(A@B^T + bias) -> bf16.
// XOR-swizzle: LDS slot kk of row r holds global k-chunk kk^(r&7) (3-bit
// involution on 128B rows -> 2-way bank aliasing = free; rule 21: linear
// gld16 dest + pre-swizzled global source).
// SCHED 1: per XCD sweep rbands fast per col (A-band L2-resident).
// ---------------------------------------------------------------------------
__global__ __launch_bounds__(256, 3) void gemm1_kernel(
    const bf16_t* __restrict__ Amat, const bf16_t* __restrict__ Bmat,
    const float* __restrict__ bias, bf16_t* __restrict__ Cmat,
    int Mrows, int Ncols, int Kd) {
  __shared__ char smem[33792];
  bf16_t* lds = (bf16_t*)smem;   // A: elements [0,8192), B: [8192,16384)
  float* sT = (float*)smem;      // GELU epilogue scratch [64][132] f32

  const int xcd = blockIdx.x & 7, t = blockIdx.x >> 3;
  const int colb = t / 13;
  const int rowb = (t % 13) * 8 + xcd;
  if (rowb >= 99) return;
  const int row0 = rowb * 128, col0 = colb * 128;

  const int tid = threadIdx.x, lane = tid & 63, wave = tid >> 6;
  const int wm = wave & 1, wn = wave >> 1;

  const bf16_t* gA[4]; const bf16_t* gB[4];
  int ldsA[4], ldsB[4];
#pragma unroll
  for (int q = 0; q < 4; ++q) {
    int c = tid + q * 256;
    int r = c >> 3, kkg = (c & 7) ^ (r & 7);
    int ra = row0 + r; if (ra > Mrows - 1) ra = Mrows - 1;  // M-edge clamp
    gA[q] = Amat + (size_t)ra * Kd + kkg * 8;
    gB[q] = Bmat + (size_t)(col0 + r) * Kd + kkg * 8;
    ldsA[q] = c * 16;
    ldsB[q] = 16384 + c * 16;
  }

  const int rl = lane & 15, kc = lane >> 4;
  int aoffs[4], boffs[4];
#pragma unroll
  for (int i = 0; i < 4; ++i) {
    int ra = wm * 64 + i * 16 + rl;
    int rb = wn * 64 + i * 16 + rl;
    aoffs[i] = ra * 64 + ((kc ^ (ra & 7)) * 8);
    boffs[i] = 8192 + rb * 64 + ((kc ^ (rb & 7)) * 8);
  }

  f32x4 acc[4][4] = {};
  const int iters = Kd / 64;

#pragma unroll
  for (int q = 0; q < 4; ++q) {
    gld16(gA[q], smem + ldsA[q]);
    gld16(gB[q], smem + ldsB[q]);
    gA[q] += 64; gB[q] += 64;
  }
  __syncthreads();

  for (int it = 0; it < iters; ++it) {
#pragma unroll
    for (int ks = 0; ks < 2; ++ks) {
      bf16x8 af[4], bfr[4];
#pragma unroll
      for (int i = 0; i < 4; ++i) af[i] = *(const bf16x8*)(lds + (aoffs[i] ^ (ks * 32)));
#pragma unroll
      for (int i = 0; i < 4; ++i) bfr[i] = *(const bf16x8*)(lds + (boffs[i] ^ (ks * 32)));
#pragma unroll
      for (int mi = 0; mi < 4; ++mi)
#pragma unroll
        for (int ni = 0; ni < 4; ++ni)
          acc[mi][ni] = __builtin_amdgcn_mfma_f32_16x16x32_bf16(
              af[mi], bfr[ni], acc[mi][ni], 0, 0, 0);
    }
    if (it + 1 < iters) {
      __syncthreads();
#pragma unroll
      for (int q = 0; q < 4; ++q) {
        gld16(gA[q], smem + ldsA[q]);
        gld16(gB[q], smem + ldsB[q]);
        gA[q] += 64; gB[q] += 64;
      }
      __syncthreads();
    }
  }

  // epilogue. C/D lane layout: col=lane&15, row=(lane>>4)*4+reg [m89-verified]
  const int crow = (lane >> 4) * 4, ccol = lane & 15;
  __syncthreads();
#pragma unroll
  for (int p = 0; p < 2; ++p) {
#pragma unroll
    for (int s = 0; s < 2; ++s) {
      int mi = 2 * p + s;
#pragma unroll
      for (int ni = 0; ni < 4; ++ni)
#pragma unroll
        for (int r = 0; r < 4; ++r)
          sT[(wm * 32 + s * 16 + crow + r) * 132 + wn * 64 + ni * 16 + ccol] =
              acc[mi][ni][r];
    }
    __syncthreads();
    const int erow = tid >> 2, eseg = tid & 3;
    const int grow = row0 + (erow >> 5) * 64 + (2 * p + ((erow >> 4) & 1)) * 16 + (erow & 15);
    if (grow < Mrows) {
      const float* src = sT + erow * 132 + eseg * 32;
      const float* bsrc = bias + col0 + eseg * 32;
      bf16_t ov[32];
#pragma unroll
      for (int i = 0; i < 32; ++i)
        ov[i] = (bf16_t)gelu_fast(src[i] + bsrc[i]);
      bf16_t* dst = Cmat + (size_t)grow * Ncols + col0 + eseg * 32;
#pragma unroll
      for (int k = 0; k < 4; ++k)
        *(bf16x8*)(dst + k * 8) = *(bf16x8*)(ov + k * 8);
    }
    __syncthreads();
  }
}

// ---------------------------------------------------------------------------
// GEMM2': 64x128 tile (M = 197*64 exact), 4 waves 2Mx2N (wave tile 32x64),
// BK=64, same proven 2-phase gload_lds structure + 3-bit XOR swizzle.
// Rationale (R5 post-mortem: MfmaUtil tracks blocks/CU): old 128x128 grid
// had 594 blocks = 2.32/CU -> makespan ~1.29x ideal; 64x128 gives 1182
// blocks = 4.62/CU (makespan ~1.08x) and LDS 24KB + ~85 VGPR -> ~5
// blocks/CU co-resident.
// Grid 1200 = 8 XCD x 150: two 4-XCD groups x 3 cols, col-fast per rband
// (W2eff 3-col group L2-resident).
// ---------------------------------------------------------------------------
__global__ __launch_bounds__(256, 4) void gemm2_kernel(
    const bf16_t* __restrict__ Amat, const bf16_t* __restrict__ Bmat,
    const float* __restrict__ bias, float* __restrict__ Cmat,
    int Mrows, int Ncols, int Kd) {
  __shared__ char smem[24576];
  bf16_t* lds = (bf16_t*)smem;   // A: elements [0,4096), B: [4096,12288)

  const int xcd = blockIdx.x & 7, t = blockIdx.x >> 3;   // t in [0,150)
  const int rowb = (t / 3) * 4 + (xcd & 3);
  if (rowb >= 197) return;
  const int colb = (xcd >> 2) * 3 + (t % 3);
  const int row0 = rowb * 64, col0 = colb * 128;

  const int tid = threadIdx.x, lane = tid & 63, wave = tid >> 6;
  const int wm = wave & 1, wn = wave >> 1;   // wm in {0,1}: 32-row half; wn in {0,1}: 64-col half

  // staging: A tile [64][64] = 512 chunks (2/thread), B [128][64] = 1024 (4/thread)
  const bf16_t* gA[2]; int ldsA[2];
  const bf16_t* gB[4]; int ldsB[4];
#pragma unroll
  for (int q = 0; q < 2; ++q) {
    int c = tid + q * 256;
    int r = c >> 3, kkg = (c & 7) ^ (r & 7);
    gA[q] = Amat + (size_t)(row0 + r) * Kd + kkg * 8;   // M exact, no clamp
    ldsA[q] = c * 16;
  }
#pragma unroll
  for (int q = 0; q < 4; ++q) {
    int c = tid + q * 256;
    int r = c >> 3, kkg = (c & 7) ^ (r & 7);
    gB[q] = Bmat + (size_t)(col0 + r) * Kd + kkg * 8;
    ldsB[q] = 8192 + c * 16;
  }

  const int rl = lane & 15, kc = lane >> 4;
  int aoffs[2], boffs[4];
#pragma unroll
  for (int i = 0; i < 2; ++i) {
    int ra = wm * 32 + i * 16 + rl;
    aoffs[i] = ra * 64 + ((kc ^ (ra & 7)) * 8);
  }
#pragma unroll
  for (int i = 0; i < 4; ++i) {
    int rb = wn * 64 + i * 16 + rl;
    boffs[i] = 4096 + rb * 64 + ((kc ^ (rb & 7)) * 8);
  }

  f32x4 acc[2][4] = {};
  const int iters = Kd / 64;   // 48

#pragma unroll
  for (int q = 0; q < 2; ++q) { gld16(gA[q], smem + ldsA[q]); gA[q] += 64; }
#pragma unroll
  for (int q = 0; q < 4; ++q) { gld16(gB[q], smem + ldsB[q]); gB[q] += 64; }
  __syncthreads();

  for (int it = 0; it < iters; ++it) {
#pragma unroll
    for (int ks = 0; ks < 2; ++ks) {
      bf16x8 af[2], bfr[4];
#pragma unroll
      for (int i = 0; i < 2; ++i) af[i] = *(const bf16x8*)(lds + (aoffs[i] ^ (ks * 32)));
#pragma unroll
      for (int i = 0; i < 4; ++i) bfr[i] = *(const bf16x8*)(lds + (boffs[i] ^ (ks * 32)));
#pragma unroll
      for (int mi = 0; mi < 2; ++mi)
#pragma unroll
        for (int ni = 0; ni < 4; ++ni)
          acc[mi][ni] = __builtin_amdgcn_mfma_f32_16x16x32_bf16(
              af[mi], bfr[ni], acc[mi][ni], 0, 0, 0);
    }
    if (it + 1 < iters) {
      __syncthreads();
#pragma unroll
      for (int q = 0; q < 2; ++q) { gld16(gA[q], smem + ldsA[q]); gA[q] += 64; }
#pragma unroll
      for (int q = 0; q < 4; ++q) { gld16(gB[q], smem + ldsB[q]); gB[q] += 64; }
      __syncthreads();
    }
  }

  // epilogue: f32 + bias, direct stores (same pattern as proven GEMM2).
  const int crow = (lane >> 4) * 4, ccol = lane & 15;
#pragma unroll
  for (int ni = 0; ni < 4; ++ni) {
    const int gc = col0 + wn * 64 + ni * 16 + ccol;
    const float bv = bias[gc];
#pragma unroll
    for (int mi = 0; mi < 2; ++mi) {
      const int gr = row0 + wm * 32 + mi * 16 + crow;
#pragma unroll
      for (int r = 0; r < 4; ++r)
        Cmat[(size_t)(gr + r) * Ncols + gc] = acc[mi][ni][r] + bv;
    }
  }
}

extern "C" void kernel_launch(void* const* d_in, const int* in_sizes, int n_in,
                              void* d_out, int out_size, void* d_ws, size_t ws_size,
                              hipStream_t stream) {
  const float* x  = (const float*)d_in[0];
  const float* W1 = (const float*)d_in[1];
  const float* b1 = (const float*)d_in[2];
  const float* A1 = (const float*)d_in[3];
  const float* B1 = (const float*)d_in[4];
  const float* W2 = (const float*)d_in[5];
  const float* b2 = (const float*)d_in[6];
  const float* A2 = (const float*)d_in[7];
  const float* B2 = (const float*)d_in[8];
  float* out = (float*)d_out;

  char* ws = (char*)d_ws;
  bf16_t* xb    = (bf16_t*)ws;                             // 19,365,888 B (pad)
  bf16_t* W1eff = (bf16_t*)(ws + 19366144);                //  4,718,592 B
  bf16_t* W2eff = (bf16_t*)(ws + 19366144 + 4718592);      //  4,718,592 B
  bf16_t* hbuf  = (bf16_t*)(ws + 19366144 + 2 * 4718592);  // 77,463,552 B

  // 1 launch: cast + fold1 + fold2 (saves 2 launch overheads)
  prep_kernel<<<CAST_BLOCKS + 2 * FOLD_BLOCKS, 256, 0, stream>>>(
      x, xb, W1, A1, B1, W1eff, W2, A2, B2, W2eff);

  // GEMM1: 99 rbands x 24 cols; per XCD 13 rbands, rband-fast -> grid 24*13*8
  gemm1_kernel<<<2496, 256, 0, stream>>>(
      xb, W1eff, b1, hbuf, M_ROWS, H_DIM, D_DIM);
  // GEMM2': 197 rbands x 6 cols; grid 8 XCD x 50 rband-strips x 3 cols = 1200
  gemm2_kernel<<<1200, 256, 0, stream>>>(
      hbuf, W2eff, b2, out, M_ROWS, D_DIM, H_DIM);
}